// Round 6
// baseline (2742.168 us; speedup 1.0000x reference)
//
#include <hip/hip_runtime.h>

using bf16x8 = __attribute__((ext_vector_type(8))) short;
using f32x4  = __attribute__((ext_vector_type(4))) float;
typedef unsigned short u16;
typedef unsigned int   u32;
using u32x2 = __attribute__((ext_vector_type(2))) u32;
using u32x4 = __attribute__((ext_vector_type(4))) u32;

#define MAX_SPIN 600000

// B=256,T=256,D=64,H=512,O=10. 64 WGs x 1024 thr (16 waves), role=wg>>4, bt=wg&15.
// role 0=A (L0 recurrence + x-proj, W_hh0+W_ih0 stationary), 1=C (L1 recurrence +
// head, W_hh1 stationary), 2/3=B0/B1 (z1 = W_ih1*h0 + b, n-halves, W_ih1-half
// stationary). All 4 WGs of a bt land on XCD bt%8 (perf-only).
// Cross-WG data: 16B global_{load,store}_dwordx4 sc0 sc1 (device-coherent),
// shipping LDS images verbatim. h0 ships as SINGLE bf16 plane (16KB); z1 ships
// f32 pre-swizzled into C's D-frag layout (img2: col = (n>>6)*64+(n&15)*4+((n>>4)&3)).
// Flags: monotonic stage counters, tid0-only poll, DELAYED publish (stage s's
// ship drains at top of s+1, then flX=s published) -> drain overlaps MFMA.
// Windows (depth-8 rings): B reads ring0[t] iff flA>=t+1; C reads z1[t] iff
// flB>=t+1; A overwrites ring0 slot s&7 iff flB0,flB1>=s-7; B overwrites
// ringz1 slot t&7 iff flC>=t-7. flC=t+1 published immediately (no stores in C).

__device__ __forceinline__ float bf2f(u16 u){ union{u32 i;float f;}v; v.i=((u32)u)<<16; return v.f; }
__device__ __forceinline__ u16 f2bf(float f){ union{float f;u32 i;}v; v.f=f; u32 x=v.i; return (u16)((x+0x7FFFu+((x>>16)&1u))>>16); }
__device__ __forceinline__ bf16x8 load8f(const float* p){
  float4 a=*(const float4*)p; float4 b=*(const float4*)(p+4);
  bf16x8 r; r[0]=(short)f2bf(a.x); r[1]=(short)f2bf(a.y); r[2]=(short)f2bf(a.z); r[3]=(short)f2bf(a.w);
  r[4]=(short)f2bf(b.x); r[5]=(short)f2bf(b.y); r[6]=(short)f2bf(b.z); r[7]=(short)f2bf(b.w); return r;
}
__device__ __forceinline__ bf16x8 pack8(float4 a, float4 b){
  bf16x8 r; r[0]=(short)f2bf(a.x); r[1]=(short)f2bf(a.y); r[2]=(short)f2bf(a.z); r[3]=(short)f2bf(a.w);
  r[4]=(short)f2bf(b.x); r[5]=(short)f2bf(b.y); r[6]=(short)f2bf(b.z); r[7]=(short)f2bf(b.w); return r;
}
__device__ __forceinline__ int  ldf(int* p){ return __hip_atomic_load(p, __ATOMIC_RELAXED, __HIP_MEMORY_SCOPE_AGENT); }
__device__ __forceinline__ void stf(int* p, int v){ __hip_atomic_store(p, v, __ATOMIC_RELAXED, __HIP_MEMORY_SCOPE_AGENT); }
__device__ __forceinline__ int waitge(int* p, int tgt){
  int v = ldf(p); int it = 0;
  while (v < tgt && ++it < MAX_SPIN){ __builtin_amdgcn_s_sleep(1); v = ldf(p); }
  return v;
}
__device__ __forceinline__ u32x4 ld128c(const u32* p){
  u32x4 r;
  asm volatile("global_load_dwordx4 %0, %1, off sc0 sc1" : "=v"(r) : "v"(p) : "memory");
  return r;
}
__device__ __forceinline__ u32x2 ld64c(const u32* p){
  u32x2 r;
  asm volatile("global_load_dwordx2 %0, %1, off sc0 sc1" : "=v"(r) : "v"(p) : "memory");
  return r;
}
__device__ __forceinline__ void st128c(u32* p, u32x4 v){
  asm volatile("global_store_dwordx4 %0, %1, off sc0 sc1" :: "v"(p), "v"(v) : "memory");
}
__device__ __forceinline__ void vmwait0(){
  asm volatile("s_waitcnt vmcnt(0)" ::: "memory");
  __builtin_amdgcn_sched_barrier(0);
}

__global__ void init_kernel(u32* p){ p[(blockIdx.x<<9) + threadIdx.x] = 0u; }

#define HFRAG(base, ks) (*(const bf16x8*)((base) + (lrow<<10) + ((((ks)<<6)+(lk8<<1)) ^ sw)))

__global__ void __launch_bounds__(1024, 1)
rnn_kernel(const float* __restrict__ x,
           const float* __restrict__ w_ih0, const float* __restrict__ w_hh0,
           const float* __restrict__ b_ih0, const float* __restrict__ b_hh0,
           const float* __restrict__ w_ih1, const float* __restrict__ w_hh1,
           const float* __restrict__ b_ih1, const float* __restrict__ b_hh1,
           const float* __restrict__ fc1_w, const float* __restrict__ fc1_b,
           const float* __restrict__ fc2_w, const float* __restrict__ fc2_b,
           float* __restrict__ out,
           u32* __restrict__ ring0, u32* __restrict__ ringz1,
           int* __restrict__ flags)
{
  const int tid  = threadIdx.x;
  const int wg   = blockIdx.x;
  const int lane = tid & 63;
  const int ww   = tid >> 6;          // 0..15
  const int role = wg >> 4;           // 0..3
  const int bt   = wg & 15;
  const int b0   = bt << 4;
  const int lrow = lane & 15;
  const int lk8  = (lane >> 4) << 3;
  const int sw   = (lrow & 7) << 4;
  const int rb   = (lane >> 4) << 2;  // D-frag row base

  __shared__ char sm[163840];
  char* smWb  = sm;                    // A/C: 4 k-slices of W_hh, 128 KB
  char* smHhi = sm + 131072;           // h hi plane [16][512] bf16, 16 KB
  char* smHlo = sm + 147456;           // h lo plane, 16 KB

  int* pA  = flags + ((bt<<2) + 0)*16;
  int* pB0 = flags + ((bt<<2) + 1)*16;
  int* pB1 = flags + ((bt<<2) + 2)*16;
  int* pC  = flags + ((bt<<2) + 3)*16;

  u32* r0bt = ring0  + bt*32768;       // 8 slots x 4096 u32 (16KB images)
  u32* z1bt = ringz1 + bt*65536;       // 8 slots x 8192 u32 (32KB images)

  if (role <= 1) {
    // ============ recurrence WG (A: layer0 + x-proj, C: layer1 + head) ============
    const float* Wp = (role == 0) ? w_hh0 : w_hh1;
    const int n0 = ww << 5;            // wave covers 32 n-cols (2 tiles)
    bf16x8 wv[24];                     // k-slices 0..11 x 2 tiles (96 VGPR)
#pragma unroll
    for (int tt = 0; tt < 2; ++tt) {
      int n = n0 + (tt<<4) + lrow;
#pragma unroll
      for (int ks = 0; ks < 12; ++ks)
        wv[tt*12+ks] = load8f(Wp + n*512 + (ks<<5) + lk8);
    }
#pragma unroll 1
    for (int it = 0; it < 8; ++it) {   // k-slices 12..15 -> LDS (128 KB)
      int cid = (it<<10) + tid;        // 0..8191
      int ss = cid >> 11, wc = cid & 2047;
      int n = wc >> 2, k0 = (wc & 3) << 3;
      bf16x8 v = load8f(Wp + n*512 + 384 + (ss<<5) + k0);
      *(bf16x8*)(smWb + (ss<<15) + (n<<6) + ((k0<<1) ^ ((n&3)<<4))) = v;
    }
    const int wl0 = ((lane>>4)<<4) ^ ((lrow&3)<<4);
    const int wlb0 = ((n0 + lrow)<<6) + wl0;
    const int wlb1 = ((n0 + 16 + lrow)<<6) + wl0;

    if (role == 0) {
      // ---------------- A ----------------
      bf16x8 wihf[4];                  // W_ih0: 2 tiles x 2 k-slices (16 VGPR)
      float biasA[2];
#pragma unroll
      for (int tt = 0; tt < 2; ++tt) {
        int n = n0 + (tt<<4) + lrow;
        wihf[tt*2+0] = load8f(w_ih0 + n*64 + lk8);
        wihf[tt*2+1] = load8f(w_ih0 + n*64 + 32 + lk8);
        biasA[tt] = b_ih0[n] + b_hh0[n];
      }
      __syncthreads();                 // LDS W-slices ready
      int fB0 = 0, fB1 = 0;
      const int q = tid << 2;          // u32 index for ship (16B/thread)

      for (int s = 0; s < 256; ++s) {
        // x loads for this stage (plain cached; same rows for every wave)
        const float* xp = x + ((b0 + lrow) << 14) + (s << 6) + lk8;
        float4 xa0 = *(const float4*)xp,        xb0 = *(const float4*)(xp + 4);
        float4 xa1 = *(const float4*)(xp + 32), xb1 = *(const float4*)(xp + 36);
        f32x4 acc[2] = {{0,0,0,0},{0,0,0,0}};
        if (s > 0) {
#pragma unroll
          for (int ks = 0; ks < 16; ++ks) {
            bf16x8 ahi = HFRAG(smHhi, ks);
            bf16x8 alo = HFRAG(smHlo, ks);
            bf16x8 bw0, bw1;
            if (ks < 12) { bw0 = wv[ks]; bw1 = wv[12+ks]; }
            else { int sb=(ks-12)<<15; bw0 = *(const bf16x8*)(smWb+sb+wlb0);
                                       bw1 = *(const bf16x8*)(smWb+sb+wlb1); }
            acc[0] = __builtin_amdgcn_mfma_f32_16x16x32_bf16(ahi, bw0, acc[0], 0,0,0);
            acc[0] = __builtin_amdgcn_mfma_f32_16x16x32_bf16(alo, bw0, acc[0], 0,0,0);
            acc[1] = __builtin_amdgcn_mfma_f32_16x16x32_bf16(ahi, bw1, acc[1], 0,0,0);
            acc[1] = __builtin_amdgcn_mfma_f32_16x16x32_bf16(alo, bw1, acc[1], 0,0,0);
          }
        }
        vmwait0();                     // prev ship drained; x arrived
        if (tid == 0) {
          if (s >= 1) stf(pA, s);      // delayed publish: ring0[s-1] visible
          if (s >= 8) {                // slot s&7 overwrite gate
            if (fB0 < s-7) fB0 = waitge(pB0, s-7);
            if (fB1 < s-7) fB1 = waitge(pB1, s-7);
          }
        }
        __syncthreads();               // also: plane(s-1) readers done
        // x-projection (single-bf16 x)
        bf16x8 xf0 = pack8(xa0, xb0), xf1 = pack8(xa1, xb1);
        acc[0] = __builtin_amdgcn_mfma_f32_16x16x32_bf16(xf0, wihf[0], acc[0], 0,0,0);
        acc[0] = __builtin_amdgcn_mfma_f32_16x16x32_bf16(xf1, wihf[1], acc[0], 0,0,0);
        acc[1] = __builtin_amdgcn_mfma_f32_16x16x32_bf16(xf0, wihf[2], acc[1], 0,0,0);
        acc[1] = __builtin_amdgcn_mfma_f32_16x16x32_bf16(xf1, wihf[3], acc[1], 0,0,0);
        // pack + plane write (hi/lo)
#pragma unroll
        for (int tt = 0; tt < 2; ++tt) {
          int cc = n0 + (tt<<4) + lrow;
#pragma unroll
          for (int r = 0; r < 4; ++r) {
            float v = acc[tt][r] + biasA[tt]; v = v > 0.f ? v : 0.f;
            u16 hi = f2bf(v), lo = f2bf(v - bf2f(hi));
            int rr = rb + r;
            int o = (rr<<10) + (((cc<<1)) ^ ((rr&7)<<4));
            *(u16*)(smHhi + o) = hi;  *(u16*)(smHlo + o) = lo;
          }
        }
        __syncthreads();
        // ship hi plane image (16KB) -> ring0 slot s&7
        st128c(r0bt + ((s&7)<<12) + q, *(const u32x4*)(smHhi + (q<<2)));
      }
      vmwait0();
      if (tid == 0) stf(pA, 256);
    } else {
      // ---------------- C ----------------
      float fB0v = 0; int fB0i = 0, fB1i = 0;
      (void)fB0v;
      __syncthreads();                 // LDS W-slices ready
      const int zoff = ((ww>>1)<<6) | (lrow<<2) | ((ww&1)<<1);
      if (tid == 0) { fB0i = waitge(pB0, 1); fB1i = waitge(pB1, 1); }
      __syncthreads();
      u32x2 zq[4];
#pragma unroll
      for (int r = 0; r < 4; ++r)
        zq[r] = ld64c(z1bt + ((rb+r)<<9) + zoff);

      for (int t = 0; t < 256; ++t) {
        f32x4 acc[2] = {{0,0,0,0},{0,0,0,0}};
        if (t > 0) {
#pragma unroll
          for (int ks = 0; ks < 16; ++ks) {
            bf16x8 ahi = HFRAG(smHhi, ks);
            bf16x8 alo = HFRAG(smHlo, ks);
            bf16x8 bw0, bw1;
            if (ks < 12) { bw0 = wv[ks]; bw1 = wv[12+ks]; }
            else { int sb=(ks-12)<<15; bw0 = *(const bf16x8*)(smWb+sb+wlb0);
                                       bw1 = *(const bf16x8*)(smWb+sb+wlb1); }
            acc[0] = __builtin_amdgcn_mfma_f32_16x16x32_bf16(ahi, bw0, acc[0], 0,0,0);
            acc[0] = __builtin_amdgcn_mfma_f32_16x16x32_bf16(alo, bw0, acc[0], 0,0,0);
            acc[1] = __builtin_amdgcn_mfma_f32_16x16x32_bf16(ahi, bw1, acc[1], 0,0,0);
            acc[1] = __builtin_amdgcn_mfma_f32_16x16x32_bf16(alo, bw1, acc[1], 0,0,0);
          }
        }
        vmwait0();                     // zq[t] ready
        __syncthreads();               // plane(t-1) readers done
#pragma unroll
        for (int tt = 0; tt < 2; ++tt) {
          int cc = n0 + (tt<<4) + lrow;
#pragma unroll
          for (int r = 0; r < 4; ++r) {
            float z = __uint_as_float(tt == 0 ? zq[r].x : zq[r].y);
            float v = acc[tt][r] + z; v = v > 0.f ? v : 0.f;
            u16 hi = f2bf(v), lo = f2bf(v - bf2f(hi));
            int rr = rb + r;
            int o = (rr<<10) + (((cc<<1)) ^ ((rr&7)<<4));
            *(u16*)(smHhi + o) = hi;  *(u16*)(smHlo + o) = lo;
          }
        }
        __syncthreads();
        if (tid == 0) {
          stf(pC, t + 1);              // z1 slot t consumed
          if (t < 255) {
            if (fB0i < t+2) fB0i = waitge(pB0, t+2);
            if (fB1i < t+2) fB1i = waitge(pB1, t+2);
          }
        }
        __syncthreads();
        if (t < 255) {
#pragma unroll
          for (int r = 0; r < 4; ++r)
            zq[r] = ld64c(z1bt + (((t+1)&7)<<13) + ((rb+r)<<9) + zoff);
        }
      }
      // ---------------- head: fc1(relu)+fc2 on local h1[255] planes ----------------
      float* smF = (float*)sm;
      if (tid < 128) {
        int r = tid >> 3, j = tid & 7;
        const float* wr = fc1_w + (j << 9);
        float accv = fc1_b[j];
        for (int k = 0; k < 512; ++k) {
          int o = (r<<10) + (((k<<1)) ^ ((r&7)<<4));
          float hv = bf2f(*(u16*)(smHhi + o)) + bf2f(*(u16*)(smHlo + o));
          accv += hv * wr[k];
        }
        smF[tid] = accv > 0.f ? accv : 0.f;
      }
      __syncthreads();
      if (tid < 160) {
        int bb = tid / 10, o = tid - bb*10;
        float accv = fc2_b[o];
        const float* w = fc2_w + (o << 3);
#pragma unroll
        for (int j = 0; j < 8; ++j) accv += smF[(bb<<3)+j] * w[j];
        out[(b0 + bb)*10 + o] = accv;
      }
    }
  } else {
    // ============ B: z1 n-half = W_ih1 * h0[t] + b ============
    char* smH = sm;                    // h0 single plane, 16 KB
    u32*  smZ = (u32*)(sm + 16384);    // img2 half [16][256] u32, 16 KB
    int* pB = (role == 2) ? pB0 : pB1;
    const int nb = (role - 2) << 8;
    const int n  = nb + (ww << 4) + lrow;   // wave owns 1 tile (16 cols)
    bf16x8 wI[16];
#pragma unroll
    for (int ks = 0; ks < 16; ++ks)
      wI[ks] = load8f(w_ih1 + n*512 + (ks<<5) + lk8);
    const float biasB = b_ih1[n] + b_hh1[n];
    const int zcol = ((ww>>2)<<6) | (lrow<<2) | (ww&3);
    const int q = tid << 2;

    int fA = 0, fC = 0;
    if (tid == 0) fA = waitge(pA, 1);
    __syncthreads();
    u32x4 hpf = ld128c(r0bt + q);      // ring0[0]

    for (int t = 0; t < 256; ++t) {
      vmwait0();                       // hpf ready; prev ship drained
      if (tid == 0) {
        if (t >= 1) stf(pB, t);        // delayed publish: z1[t-1] visible
        if (t >= 8 && fC < t-7) fC = waitge(pC, t-7);       // z1 slot gate
        if (t < 255 && fA < t+2) fA = waitge(pA, t+2);      // h0[t+1] ready?
      }
      __syncthreads();                 // (also gates plane write vs prev MFMA)
      *(u32x4*)(smH + (q<<2)) = hpf;   // h0[t] plane
      __syncthreads();
      if (t < 255) hpf = ld128c(r0bt + (((t+1)&7)<<12) + q);
      f32x4 acc = {0,0,0,0};
#pragma unroll
      for (int ks = 0; ks < 16; ++ks) {
        bf16x8 af = HFRAG(smH, ks);
        acc = __builtin_amdgcn_mfma_f32_16x16x32_bf16(af, wI[ks], acc, 0,0,0);
      }
#pragma unroll
      for (int r = 0; r < 4; ++r)
        smZ[((rb+r)<<8) | zcol] = __float_as_uint(acc[r] + biasB);
      __syncthreads();
      {                                // ship img2 half (16KB) -> ringz1 slot t&7
        int row = q >> 8, c = q & 255;
        st128c(z1bt + ((t&7)<<13) + (row<<9) + nb + c, *(const u32x4*)((const char*)smZ + (q<<2)));
      }
    }
    vmwait0();
    if (tid == 0) stf(pB, 256);
  }
}

extern "C" void kernel_launch(void* const* d_in, const int* in_sizes, int n_in,
                              void* d_out, int out_size, void* d_ws, size_t ws_size,
                              hipStream_t stream) {
  const float* x     = (const float*)d_in[0];
  const float* w_ih0 = (const float*)d_in[1];
  const float* w_hh0 = (const float*)d_in[2];
  const float* b_ih0 = (const float*)d_in[3];
  const float* b_hh0 = (const float*)d_in[4];
  const float* w_ih1 = (const float*)d_in[5];
  const float* w_hh1 = (const float*)d_in[6];
  const float* b_ih1 = (const float*)d_in[7];
  const float* b_hh1 = (const float*)d_in[8];
  const float* fc1_w = (const float*)d_in[9];
  const float* fc1_b = (const float*)d_in[10];
  const float* fc2_w = (const float*)d_in[11];
  const float* fc2_b = (const float*)d_in[12];
  float* out = (float*)d_out;

  char* ws = (char*)d_ws;
  u32* ring0  = (u32*)(ws);                  // h0 bf16-plane images: 16bt x 8 x 16KB = 2MB
  u32* ringz1 = (u32*)(ws + (2u<<20));       // z1 f32 img2: 16bt x 8 x 32KB = 4MB
  int* flags  = (int*)(ws + (6u<<20));       // 16bt x 4 x 64B = 4KB

  init_kernel<<<dim3(2), dim3(512), 0, stream>>>((u32*)(ws + (6u<<20)));
  rnn_kernel<<<dim3(64), dim3(1024), 0, stream>>>(
      x, w_ih0, w_hh0, b_ih0, b_hh0, w_ih1, w_hh1, b_ih1, b_hh1,
      fc1_w, fc1_b, fc2_w, fc2_b, out,
      ring0, ringz1, flags);
}